// Round 1
// baseline (1073.656 us; speedup 1.0000x reference)
//
#include <hip/hip_runtime.h>
#include <hip/hip_bf16.h>
#include <cstdint>

#define S_LEN   4608
#define HID     2048
#define VOCAB_N 32768
#define CAPV    30.0f
#define IGNORE_IDX (-100)
#define NT512   512   // vocab partial tiles of 64 columns

typedef short bf16x8 __attribute__((ext_vector_type(8)));
typedef float f32x4  __attribute__((ext_vector_type(4)));

// ---------- helpers ----------
__device__ __forceinline__ unsigned short f2bf_rtne(float f) {
    unsigned int u = __float_as_uint(f);
    unsigned int r = u + 0x7fffu + ((u >> 16) & 1u);
    return (unsigned short)(r >> 16);
}
__device__ __forceinline__ float bf_lo(unsigned int u) { return __uint_as_float(u << 16); }
__device__ __forceinline__ float bf_hi(unsigned int u) { return __uint_as_float(u & 0xffff0000u); }
__device__ __forceinline__ float bfdot2(unsigned int x, unsigned int w) {
    return bf_lo(x) * bf_lo(w) + bf_hi(x) * bf_hi(w);
}
// z = CAP * tanh(logit/CAP)
__device__ __forceinline__ float softcap(float logit) {
    float e = __expf(logit * (2.0f / CAPV));
    return CAPV * (e - 1.0f) / (e + 1.0f);
}

// ---------- kernel 0: fp32 -> bf16 convert of hidden ----------
__global__ void cvt_kernel(const float* __restrict__ h, unsigned short* __restrict__ xb) {
    int i = blockIdx.x * blockDim.x + threadIdx.x;   // one float4 per thread, exact cover
    float4 v = ((const float4*)h)[i];
    ushort4 o;
    o.x = f2bf_rtne(v.x); o.y = f2bf_rtne(v.y);
    o.z = f2bf_rtne(v.z); o.w = f2bf_rtne(v.w);
    ((ushort4*)xb)[i] = o;
}

// ---------- kernel 1: fused GEMM + softcap + per-row partial sum-exp ----------
// Grid: (VOCAB_N/128, S_LEN/128), block 256 (4 waves, 2x2 over the 128x128 tile).
// partL[row * 512 + ntile64] = sum over 64 vocab cols of exp(softcap(logit))
__global__ __launch_bounds__(256)
void gemm_lse_kernel(const unsigned short* __restrict__ X,
                     const unsigned short* __restrict__ W,
                     float* __restrict__ partL) {
    __shared__ __align__(16) unsigned short As[128 * 32];
    __shared__ __align__(16) unsigned short Bs[128 * 32];

    const int tid  = threadIdx.x;
    const int wave = tid >> 6;
    const int lane = tid & 63;
    const int tileM = blockIdx.y * 128;
    const int tileN = blockIdx.x * 128;

    // staging lane map: 16 rows x 64B per wave-issue, lane -> row lane/4, 16B chunk lane%4
    const int lr = lane >> 2;
    const int lc = (lane & 3) * 8;

    const unsigned short* Abase = X + (size_t)(tileM + wave * 32) * HID;
    const unsigned short* Bbase = W + (size_t)(tileN + wave * 32) * HID;

    const int wr  = wave >> 1, wc = wave & 1;     // 2x2 wave layout, 64x64 each
    const int q   = lane >> 4, l16 = lane & 15;

    f32x4 acc[4][4] = {};

    for (int k0 = 0; k0 < HID; k0 += 32) {
        __syncthreads();   // protect LDS from previous iteration's readers
        #pragma unroll
        for (int j = 0; j < 2; ++j) {
            const unsigned short* ga = Abase + (size_t)(j * 16 + lr) * HID + k0 + lc;
            __builtin_amdgcn_global_load_lds(
                (const __attribute__((address_space(1))) void*)ga,
                (__attribute__((address_space(3))) void*)&As[(wave * 32 + j * 16) * 32],
                16, 0, 0);
            const unsigned short* gb = Bbase + (size_t)(j * 16 + lr) * HID + k0 + lc;
            __builtin_amdgcn_global_load_lds(
                (const __attribute__((address_space(1))) void*)gb,
                (__attribute__((address_space(3))) void*)&Bs[(wave * 32 + j * 16) * 32],
                16, 0, 0);
        }
        __syncthreads();   // drains vmcnt for the LDS-direct loads

        bf16x8 av[4], bv[4];
        #pragma unroll
        for (int t = 0; t < 4; ++t) {
            av[t] = *(const bf16x8*)&As[(wr * 64 + t * 16 + l16) * 32 + q * 8];
            bv[t] = *(const bf16x8*)&Bs[(wc * 64 + t * 16 + l16) * 32 + q * 8];
        }
        #pragma unroll
        for (int ti = 0; ti < 4; ++ti)
            #pragma unroll
            for (int tj = 0; tj < 4; ++tj)
                acc[ti][tj] = __builtin_amdgcn_mfma_f32_16x16x32_bf16(
                    av[ti], bv[tj], acc[ti][tj], 0, 0, 0);
    }

    // Epilogue: C layout col = lane&15 (vocab), row = q*4 + reg (seq).
    // Per (ti, reg): one seq row; sum exp(softcap) over 4 col-tiles then 16 lanes.
    const int rowbase = tileM + wr * 64;
    const int ntile   = blockIdx.x * 2 + wc;
    #pragma unroll
    for (int ti = 0; ti < 4; ++ti) {
        #pragma unroll
        for (int r = 0; r < 4; ++r) {
            float s = 0.0f;
            #pragma unroll
            for (int tj = 0; tj < 4; ++tj)
                s += __expf(softcap(acc[ti][tj][r]));
            s += __shfl_xor(s, 1);
            s += __shfl_xor(s, 2);
            s += __shfl_xor(s, 4);
            s += __shfl_xor(s, 8);
            if (l16 == 0)
                partL[(size_t)(rowbase + ti * 16 + q * 4 + r) * NT512 + ntile] = s;
        }
    }
}

// ---------- kernel 2: per-row label logit + logsumexp reduce -> row_loss ----------
__global__ void row_reduce_kernel(const unsigned short* __restrict__ X,
                                  const unsigned short* __restrict__ W,
                                  const int* __restrict__ ids,
                                  const int* __restrict__ am,
                                  const float* __restrict__ partL,
                                  float* __restrict__ row_loss) {
    const int wave = threadIdx.x >> 6;
    const int lane = threadIdx.x & 63;
    const int r = blockIdx.x * 4 + wave;

    int lab = IGNORE_IDX;
    if (r < S_LEN - 1 && am[r + 1] != 0) lab = ids[r + 1];
    const bool valid = (lab >= 0 && lab < VOCAB_N);

    float dot = 0.0f;
    if (valid) {
        const unsigned short* xr = X + (size_t)r   * HID;
        const unsigned short* wr = W + (size_t)lab * HID;
        #pragma unroll
        for (int c = 0; c < 4; ++c) {
            const int off = c * 512 + lane * 8;
            uint4 xu = *(const uint4*)(xr + off);
            uint4 wu = *(const uint4*)(wr + off);
            dot += bfdot2(xu.x, wu.x) + bfdot2(xu.y, wu.y) +
                   bfdot2(xu.z, wu.z) + bfdot2(xu.w, wu.w);
        }
    }
    #pragma unroll
    for (int m = 1; m < 64; m <<= 1) dot += __shfl_xor(dot, m);

    float L = 0.0f;
    const float* pr = partL + (size_t)r * NT512;
    #pragma unroll
    for (int i = 0; i < 8; ++i) L += pr[i * 64 + lane];
    #pragma unroll
    for (int m = 1; m < 64; m <<= 1) L += __shfl_xor(L, m);

    if (lane == 0) {
        float loss = 0.0f;
        if (valid) loss = logf(L) - softcap(dot);
        row_loss[r] = loss;
    }
}

// ---------- kernel 3: final scalar sum ----------
__global__ void final_sum_kernel(const float* __restrict__ row_loss, float* __restrict__ out) {
    __shared__ float sm[256];
    float s = 0.0f;
    for (int i = threadIdx.x; i < S_LEN; i += 256) s += row_loss[i];
    sm[threadIdx.x] = s;
    __syncthreads();
    for (int st = 128; st > 0; st >>= 1) {
        if (threadIdx.x < st) sm[threadIdx.x] += sm[threadIdx.x + st];
        __syncthreads();
    }
    if (threadIdx.x == 0) out[0] = sm[0];
}

extern "C" void kernel_launch(void* const* d_in, const int* in_sizes, int n_in,
                              void* d_out, int out_size, void* d_ws, size_t ws_size,
                              hipStream_t stream) {
    const unsigned short* W  = (const unsigned short*)d_in[0];  // bf16 [V, H]
    const float*  hidden     = (const float*)d_in[1];           // fp32 [1, S, H]
    const int*    ids        = (const int*)d_in[2];             // [1, S]
    const int*    am         = (const int*)d_in[3];             // [1, S]
    float* out = (float*)d_out;

    char* ws = (char*)d_ws;
    unsigned short* Xb   = (unsigned short*)ws;                                    // S*H bf16
    float* partL         = (float*)(ws + (size_t)S_LEN * HID * 2);                 // S*512 f32
    float* row_loss      = (float*)(ws + (size_t)S_LEN * HID * 2
                                       + (size_t)S_LEN * NT512 * 4);               // S f32

    cvt_kernel<<<(S_LEN * HID / 4) / 256, 256, 0, stream>>>(hidden, Xb);

    dim3 g(VOCAB_N / 128, S_LEN / 128);
    gemm_lse_kernel<<<g, 256, 0, stream>>>(Xb, W, partL);

    row_reduce_kernel<<<S_LEN / 4, 256, 0, stream>>>(Xb, W, ids, am, partL, row_loss);

    final_sum_kernel<<<1, 256, 0, stream>>>(row_loss, out);
}